// Round 1
// baseline (819.315 us; speedup 1.0000x reference)
//
#include <hip/hip_runtime.h>
#include <stdint.h>

// Problem constants
#define BATCH 2
#define SEQ   2048
#define DEMB  1024
#define NHEAD 16
#define DK    64
#define NTOK  (BATCH * SEQ)               // 4096
#define OUT_ELEMS ((size_t)NTOK * DEMB)   // 4194304

typedef __bf16 bf16x8 __attribute__((ext_vector_type(8)));
typedef float  f32x4  __attribute__((ext_vector_type(4)));

union FragU { uint4 u; bf16x8 b; };

__device__ __forceinline__ unsigned short f2bf(float f) {
  union { float f; unsigned u; } v; v.f = f;
  unsigned r = v.u + 0x7fffu + ((v.u >> 16) & 1u);   // RNE
  return (unsigned short)(r >> 16);
}

// ---------------------------------------------------------------------------
// Kernel 1: QKV projections.  Y = X @ W^T + b   (X [4096,1024] fp32, W [o,i])
// q -> qh [B,H,S,64] bf16 ; k -> kh [B,H,S,64] bf16 ; v -> vt [B,H,64,S] bf16
// 128x128 block tile, BK=64, 4 waves (2x2), each wave 4x4 of 16x16x32 MFMA.
// LDS padded to 72 shorts/row: row stride 144 B -> 2-way bank alias (free).
// ---------------------------------------------------------------------------
__global__ __launch_bounds__(256) void k_proj(
    const float* __restrict__ Xq, const float* __restrict__ Xk, const float* __restrict__ Xv,
    const float* __restrict__ Wq, const float* __restrict__ bq,
    const float* __restrict__ Wk, const float* __restrict__ bk,
    const float* __restrict__ Wv, const float* __restrict__ bv,
    unsigned short* __restrict__ qh, unsigned short* __restrict__ kh,
    unsigned short* __restrict__ vt)
{
  const int p = blockIdx.z;
  const float* __restrict__ X    = (p == 0) ? Xq : (p == 1) ? Xk : Xv;
  const float* __restrict__ W    = (p == 0) ? Wq : (p == 1) ? Wk : Wv;
  const float* __restrict__ bias = (p == 0) ? bq : (p == 1) ? bk : bv;

  __shared__ unsigned short As[128][72];
  __shared__ unsigned short Bs[128][72];

  const int tid  = threadIdx.x;
  const int lane = tid & 63;
  const int w    = tid >> 6;
  const int wm   = (w & 1) * 64;
  const int wn   = (w >> 1) * 64;
  const int l15  = lane & 15;
  const int quad = lane >> 4;

  const int row0 = blockIdx.x * 128;   // token rows
  const int col0 = blockIdx.y * 128;   // out-feature cols

  f32x4 acc[4][4];
#pragma unroll
  for (int mi = 0; mi < 4; ++mi)
#pragma unroll
    for (int ni = 0; ni < 4; ++ni) acc[mi][ni] = {0.f, 0.f, 0.f, 0.f};

  for (int kk = 0; kk < DEMB; kk += 64) {
    // stage A (X) and B (W) tiles: 128x64 fp32 -> bf16 in LDS
#pragma unroll
    for (int r8 = 0; r8 < 8; ++r8) {
      int row = r8 * 16 + (tid >> 4);
      int c4  = tid & 15;
      float4 a = *(const float4*)&X[(size_t)(row0 + row) * DEMB + kk + c4 * 4];
      ushort4 pa; pa.x = f2bf(a.x); pa.y = f2bf(a.y); pa.z = f2bf(a.z); pa.w = f2bf(a.w);
      *(ushort4*)&As[row][c4 * 4] = pa;
      float4 b = *(const float4*)&W[(size_t)(col0 + row) * DEMB + kk + c4 * 4];
      ushort4 pb; pb.x = f2bf(b.x); pb.y = f2bf(b.y); pb.z = f2bf(b.z); pb.w = f2bf(b.w);
      *(ushort4*)&Bs[row][c4 * 4] = pb;
    }
    __syncthreads();
#pragma unroll
    for (int k0 = 0; k0 < 64; k0 += 32) {
      FragU af[4], bfr[4];
#pragma unroll
      for (int mi = 0; mi < 4; ++mi)
        af[mi].u = *(const uint4*)&As[wm + mi * 16 + l15][k0 + quad * 8];
#pragma unroll
      for (int ni = 0; ni < 4; ++ni)
        bfr[ni].u = *(const uint4*)&Bs[wn + ni * 16 + l15][k0 + quad * 8];
#pragma unroll
      for (int mi = 0; mi < 4; ++mi)
#pragma unroll
        for (int ni = 0; ni < 4; ++ni)
          acc[mi][ni] = __builtin_amdgcn_mfma_f32_16x16x32_bf16(af[mi].b, bfr[ni].b, acc[mi][ni], 0, 0, 0);
    }
    __syncthreads();
  }

  // epilogue: bias + scatter to head layouts (C/D: col=lane&15, row=quad*4+i)
#pragma unroll
  for (int mi = 0; mi < 4; ++mi) {
#pragma unroll
    for (int ni = 0; ni < 4; ++ni) {
      int o = col0 + wn + ni * 16 + l15;
      float bv_ = bias[o];
      int h_ = o >> 6, d_ = o & 63;
#pragma unroll
      for (int i = 0; i < 4; ++i) {
        int t  = row0 + wm + mi * 16 + quad * 4 + i;
        int b_ = t >> 11, s_ = t & 2047;
        unsigned short val = f2bf(acc[mi][ni][i] + bv_);
        if (p == 0)
          qh[(((size_t)b_ * NHEAD + h_) * SEQ + s_) * DK + d_] = val;
        else if (p == 1)
          kh[(((size_t)b_ * NHEAD + h_) * SEQ + s_) * DK + d_] = val;
        else
          vt[(((size_t)b_ * NHEAD + h_) * DK + d_) * SEQ + s_] = val;
      }
    }
  }
}

// ---------------------------------------------------------------------------
// Kernel 2: per (head, 64-row block): scores = Q Kt / 8, softmax, write P fp32
// to d_out, fused PV -> blended bf16.  Two QK passes (recompute) so no giant
// LDS P buffer is needed; no max-subtraction (scores ~N(0,1), fp32-safe).
// ---------------------------------------------------------------------------
__global__ __launch_bounds__(256) void k_attn(
    const unsigned short* __restrict__ qh, const unsigned short* __restrict__ kh,
    const unsigned short* __restrict__ vt, unsigned short* __restrict__ blended,
    float* __restrict__ Pout)
{
  const int bh = blockIdx.y;            // 0..31  (b*16+h)
  const int s0 = blockIdx.x * 64;       // query-row block
  const size_t hoff = (size_t)bh * SEQ * DK;   // elems, same for qh/kh/vt

  __shared__ unsigned short Qs[64][72];
  __shared__ unsigned short Ks[64][72];
  __shared__ unsigned short Ps[64][72];
  __shared__ float rowpart[4][64];
  __shared__ float recipS[64];

  const int tid  = threadIdx.x;
  const int lane = tid & 63;
  const int w    = tid >> 6;
  const int l15  = lane & 15;
  const int quad = lane >> 4;

  // stage Q tile (64x64 bf16, contiguous in qh)
#pragma unroll
  for (int r = 0; r < 2; ++r) {
    int idx = tid + r * 256;
    int row = idx >> 3, c = (idx & 7) * 8;
    uint4 v = *(const uint4*)&qh[hoff + (size_t)(s0 + row) * DK + c];
    *(uint4*)&Qs[row][c] = v;
  }

  float rs[4][4];
#pragma unroll
  for (int mi = 0; mi < 4; ++mi)
#pragma unroll
    for (int i = 0; i < 4; ++i) rs[mi][i] = 0.f;

  // ---- PASS 1: exp row-sums ----
  for (int t0 = 0; t0 < SEQ; t0 += 64) {
    __syncthreads();
#pragma unroll
    for (int r = 0; r < 2; ++r) {
      int idx = tid + r * 256;
      int row = idx >> 3, c = (idx & 7) * 8;
      uint4 v = *(const uint4*)&kh[hoff + (size_t)(t0 + row) * DK + c];
      *(uint4*)&Ks[row][c] = v;
    }
    __syncthreads();
    FragU bfr[2];
#pragma unroll
    for (int k0 = 0; k0 < 2; ++k0)
      bfr[k0].u = *(const uint4*)&Ks[w * 16 + l15][k0 * 32 + quad * 8];
#pragma unroll
    for (int mi = 0; mi < 4; ++mi) {
      f32x4 a = {0.f, 0.f, 0.f, 0.f};
#pragma unroll
      for (int k0 = 0; k0 < 2; ++k0) {
        FragU af; af.u = *(const uint4*)&Qs[mi * 16 + l15][k0 * 32 + quad * 8];
        a = __builtin_amdgcn_mfma_f32_16x16x32_bf16(af.b, bfr[k0].b, a, 0, 0, 0);
      }
#pragma unroll
      for (int i = 0; i < 4; ++i) rs[mi][i] += __expf(a[i] * 0.125f);
    }
  }

  // reduce row sums: over 16 cols (lanes) then over 4 waves via LDS
#pragma unroll
  for (int mi = 0; mi < 4; ++mi)
#pragma unroll
    for (int i = 0; i < 4; ++i) {
      float v = rs[mi][i];
      v += __shfl_xor(v, 1); v += __shfl_xor(v, 2);
      v += __shfl_xor(v, 4); v += __shfl_xor(v, 8);
      rs[mi][i] = v;
    }
  if (l15 == 0) {
#pragma unroll
    for (int mi = 0; mi < 4; ++mi)
#pragma unroll
      for (int i = 0; i < 4; ++i) rowpart[w][mi * 16 + quad * 4 + i] = rs[mi][i];
  }
  __syncthreads();
  if (tid < 64)
    recipS[tid] = 1.0f / (rowpart[0][tid] + rowpart[1][tid] + rowpart[2][tid] + rowpart[3][tid]);
  __syncthreads();
  float rcp[4][4];
#pragma unroll
  for (int mi = 0; mi < 4; ++mi)
#pragma unroll
    for (int i = 0; i < 4; ++i) rcp[mi][i] = recipS[mi * 16 + quad * 4 + i];

  // ---- PASS 2: recompute, write normalized P, fused PV ----
  f32x4 accpv[4];
#pragma unroll
  for (int mi = 0; mi < 4; ++mi) accpv[mi] = {0.f, 0.f, 0.f, 0.f};

  for (int t0 = 0; t0 < SEQ; t0 += 64) {
    __syncthreads();
#pragma unroll
    for (int r = 0; r < 2; ++r) {
      int idx = tid + r * 256;
      int row = idx >> 3, c = (idx & 7) * 8;
      uint4 v = *(const uint4*)&kh[hoff + (size_t)(t0 + row) * DK + c];
      *(uint4*)&Ks[row][c] = v;
    }
    __syncthreads();
    FragU bfr[2];
#pragma unroll
    for (int k0 = 0; k0 < 2; ++k0)
      bfr[k0].u = *(const uint4*)&Ks[w * 16 + l15][k0 * 32 + quad * 8];
#pragma unroll
    for (int mi = 0; mi < 4; ++mi) {
      f32x4 a = {0.f, 0.f, 0.f, 0.f};
#pragma unroll
      for (int k0 = 0; k0 < 2; ++k0) {
        FragU af; af.u = *(const uint4*)&Qs[mi * 16 + l15][k0 * 32 + quad * 8];
        a = __builtin_amdgcn_mfma_f32_16x16x32_bf16(af.b, bfr[k0].b, a, 0, 0, 0);
      }
#pragma unroll
      for (int i = 0; i < 4; ++i) {
        float e = __expf(a[i] * 0.125f) * rcp[mi][i];
        int row = mi * 16 + quad * 4 + i;
        int col = t0 + w * 16 + l15;
        Pout[((size_t)bh * SEQ + s0 + row) * SEQ + col] = e;   // normalized fp32 P
        Ps[row][w * 16 + l15] = f2bf(e);                       // bf16 for PV A-operand
      }
    }
    __syncthreads();
    // PV for this 64-wide t-tile: A = Ps [s][t], B = V^T rows (d, t-contiguous)
    FragU bpv[2];
#pragma unroll
    for (int k0 = 0; k0 < 2; ++k0)
      bpv[k0].u = *(const uint4*)&vt[hoff + (size_t)(w * 16 + l15) * SEQ + t0 + k0 * 32 + quad * 8];
#pragma unroll
    for (int mi = 0; mi < 4; ++mi) {
#pragma unroll
      for (int k0 = 0; k0 < 2; ++k0) {
        FragU apv; apv.u = *(const uint4*)&Ps[mi * 16 + l15][k0 * 32 + quad * 8];
        accpv[mi] = __builtin_amdgcn_mfma_f32_16x16x32_bf16(apv.b, bpv[k0].b, accpv[mi], 0, 0, 0);
      }
    }
  }

  // blended epilogue -> ws [token][h*64+d] bf16
  const int b_ = bh >> 4, h_ = bh & 15;
#pragma unroll
  for (int mi = 0; mi < 4; ++mi)
#pragma unroll
    for (int i = 0; i < 4; ++i) {
      int row   = mi * 16 + quad * 4 + i;
      int token = b_ * SEQ + s0 + row;
      int d     = w * 16 + l15;
      blended[(size_t)token * DEMB + h_ * DK + d] = f2bf(accpv[mi][i]);
    }
}

// ---------------------------------------------------------------------------
// Kernel 3: out = blended @ Wo^T + bo   (blended bf16 [4096,1024], out fp32)
// ---------------------------------------------------------------------------
__global__ __launch_bounds__(256) void k_outproj(
    const unsigned short* __restrict__ blended, const float* __restrict__ Wo,
    const float* __restrict__ bo, float* __restrict__ out)
{
  __shared__ unsigned short As[128][72];
  __shared__ unsigned short Bs[128][72];

  const int tid  = threadIdx.x;
  const int lane = tid & 63;
  const int w    = tid >> 6;
  const int wm   = (w & 1) * 64;
  const int wn   = (w >> 1) * 64;
  const int l15  = lane & 15;
  const int quad = lane >> 4;

  const int row0 = blockIdx.x * 128;
  const int col0 = blockIdx.y * 128;

  f32x4 acc[4][4];
#pragma unroll
  for (int mi = 0; mi < 4; ++mi)
#pragma unroll
    for (int ni = 0; ni < 4; ++ni) acc[mi][ni] = {0.f, 0.f, 0.f, 0.f};

  for (int kk = 0; kk < DEMB; kk += 64) {
    // stage A: bf16 direct copy
#pragma unroll
    for (int r4 = 0; r4 < 4; ++r4) {
      int row = r4 * 32 + (tid >> 3);
      int c   = (tid & 7) * 8;
      uint4 v = *(const uint4*)&blended[(size_t)(row0 + row) * DEMB + kk + c];
      *(uint4*)&As[row][c] = v;
    }
    // stage B: Wo fp32 -> bf16
#pragma unroll
    for (int r8 = 0; r8 < 8; ++r8) {
      int row = r8 * 16 + (tid >> 4);
      int c4  = tid & 15;
      float4 b = *(const float4*)&Wo[(size_t)(col0 + row) * DEMB + kk + c4 * 4];
      ushort4 pb; pb.x = f2bf(b.x); pb.y = f2bf(b.y); pb.z = f2bf(b.z); pb.w = f2bf(b.w);
      *(ushort4*)&Bs[row][c4 * 4] = pb;
    }
    __syncthreads();
#pragma unroll
    for (int k0 = 0; k0 < 64; k0 += 32) {
      FragU af[4], bfr[4];
#pragma unroll
      for (int mi = 0; mi < 4; ++mi)
        af[mi].u = *(const uint4*)&As[wm + mi * 16 + l15][k0 + quad * 8];
#pragma unroll
      for (int ni = 0; ni < 4; ++ni)
        bfr[ni].u = *(const uint4*)&Bs[wn + ni * 16 + l15][k0 + quad * 8];
#pragma unroll
      for (int mi = 0; mi < 4; ++mi)
#pragma unroll
        for (int ni = 0; ni < 4; ++ni)
          acc[mi][ni] = __builtin_amdgcn_mfma_f32_16x16x32_bf16(af[mi].b, bfr[ni].b, acc[mi][ni], 0, 0, 0);
    }
    __syncthreads();
  }

#pragma unroll
  for (int mi = 0; mi < 4; ++mi)
#pragma unroll
    for (int ni = 0; ni < 4; ++ni) {
      int o = col0 + wn + ni * 16 + l15;
      float bv_ = bo[o];
#pragma unroll
      for (int i = 0; i < 4; ++i) {
        int t = row0 + wm + mi * 16 + quad * 4 + i;
        out[(size_t)t * DEMB + o] = acc[mi][ni][i] + bv_;
      }
    }
}

// ---------------------------------------------------------------------------
extern "C" void kernel_launch(void* const* d_in, const int* in_sizes, int n_in,
                              void* d_out, int out_size, void* d_ws, size_t ws_size,
                              hipStream_t stream) {
  const float* Xq = (const float*)d_in[0];
  const float* Xk = (const float*)d_in[1];
  const float* Xv = (const float*)d_in[2];
  const float* Wq = (const float*)d_in[3];
  const float* bq = (const float*)d_in[4];
  const float* Wk = (const float*)d_in[5];
  const float* bk = (const float*)d_in[6];
  const float* Wv = (const float*)d_in[7];
  const float* bv = (const float*)d_in[8];
  const float* Wo = (const float*)d_in[9];
  const float* bo = (const float*)d_in[10];

  float* out  = (float*)d_out;
  float* Pout = out + OUT_ELEMS;   // attention_score region

  // ws: 4 x 8MB bf16 buffers (qh, kh, vt, blended) = 32 MB
  unsigned short* qh      = (unsigned short*)d_ws;
  unsigned short* kh      = qh + OUT_ELEMS;
  unsigned short* vt      = kh + OUT_ELEMS;
  unsigned short* blended = vt + OUT_ELEMS;

  k_proj<<<dim3(32, 8, 3), 256, 0, stream>>>(Xq, Xk, Xv, Wq, bq, Wk, bk, Wv, bv, qh, kh, vt);
  k_attn<<<dim3(SEQ / 64, BATCH * NHEAD), 256, 0, stream>>>(qh, kh, vt, blended, Pout);
  k_outproj<<<dim3(32, 8), 256, 0, stream>>>(blended, Wo, bo, out);
}

// Round 2
// 787.760 us; speedup vs baseline: 1.0401x; 1.0401x over previous
//
#include <hip/hip_runtime.h>
#include <stdint.h>

#define BATCH 2
#define SEQ   2048
#define DEMB  1024
#define NHEAD 16
#define DK    64
#define NTOK  (BATCH * SEQ)               // 4096
#define OUT_ELEMS ((size_t)NTOK * DEMB)   // 4194304

typedef __bf16 bf16x8 __attribute__((ext_vector_type(8)));
typedef float  f32x4  __attribute__((ext_vector_type(4)));
union FragU { uint4 u; bf16x8 b; };

__device__ __forceinline__ unsigned short f2bf(float f) {
  union { float f; unsigned u; } v; v.f = f;
  unsigned r = v.u + 0x7fffu + ((v.u >> 16) & 1u);   // RNE
  return (unsigned short)(r >> 16);
}

// async global->LDS, 16B per lane. LDS dest must be wave-uniform base + lane*16.
__device__ __forceinline__ void gll16(const void* g, void* l) {
  __builtin_amdgcn_global_load_lds(
      (const __attribute__((address_space(1))) void*)g,
      (__attribute__((address_space(3))) void*)l, 16, 0, 0);
}

// ---------------------------------------------------------------------------
// k_cvt: fp32 -> bf16 for the 3 activations and 4 weight matrices (once).
// ---------------------------------------------------------------------------
__global__ __launch_bounds__(256) void k_cvt(
    const float* __restrict__ q, const float* __restrict__ k, const float* __restrict__ v,
    const float* __restrict__ wq, const float* __restrict__ wk,
    const float* __restrict__ wv, const float* __restrict__ wo,
    unsigned short* __restrict__ dq, unsigned short* __restrict__ dk,
    unsigned short* __restrict__ dv, unsigned short* __restrict__ dwq,
    unsigned short* __restrict__ dwk, unsigned short* __restrict__ dwv,
    unsigned short* __restrict__ dwo)
{
  const int t = blockIdx.y;
  const float* s; unsigned short* d; int n4;
  switch (t) {
    case 0: s = q;  d = dq;  n4 = NTOK * DEMB / 4; break;
    case 1: s = k;  d = dk;  n4 = NTOK * DEMB / 4; break;
    case 2: s = v;  d = dv;  n4 = NTOK * DEMB / 4; break;
    case 3: s = wq; d = dwq; n4 = DEMB * DEMB / 4; break;
    case 4: s = wk; d = dwk; n4 = DEMB * DEMB / 4; break;
    case 5: s = wv; d = dwv; n4 = DEMB * DEMB / 4; break;
    default: s = wo; d = dwo; n4 = DEMB * DEMB / 4; break;
  }
  for (int i = blockIdx.x * 256 + threadIdx.x; i < n4; i += gridDim.x * 256) {
    float4 f = ((const float4*)s)[i];
    ushort4 o; o.x = f2bf(f.x); o.y = f2bf(f.y); o.z = f2bf(f.z); o.w = f2bf(f.w);
    ((ushort4*)d)[i] = o;
  }
}

// ---------------------------------------------------------------------------
// k_proj: Y^T tile GEMM: D[m=o][n=token] = sum_k W[o][k] * X[token][k] + b[o]
// Operand swap puts 4 consecutive out-features in each lane -> ushort4 stores.
// global_load_lds staging, unpadded LDS (m97 structure).
// Outputs token-major head layouts qh/kh/vh [B,H,S,64] bf16.
// ---------------------------------------------------------------------------
__global__ __launch_bounds__(256) void k_proj(
    const unsigned short* __restrict__ Xqb, const unsigned short* __restrict__ Xkb,
    const unsigned short* __restrict__ Xvb,
    const unsigned short* __restrict__ Wqb, const unsigned short* __restrict__ Wkb,
    const unsigned short* __restrict__ Wvb,
    const float* __restrict__ bq, const float* __restrict__ bk, const float* __restrict__ bv,
    unsigned short* __restrict__ qh, unsigned short* __restrict__ kh,
    unsigned short* __restrict__ vh)
{
  const int p = blockIdx.z;
  const unsigned short* __restrict__ X = (p == 0) ? Xqb : (p == 1) ? Xkb : Xvb;
  const unsigned short* __restrict__ W = (p == 0) ? Wqb : (p == 1) ? Wkb : Wvb;
  const float* __restrict__ bias       = (p == 0) ? bq  : (p == 1) ? bk  : bv;
  unsigned short* __restrict__ dst     = (p == 0) ? qh  : (p == 1) ? kh  : vh;

  __shared__ unsigned short As[128][64];   // W rows (m = o)
  __shared__ unsigned short Bs[128][64];   // X rows (n = token)

  const int tid  = threadIdx.x;
  const int lane = tid & 63;
  const int w    = tid >> 6;
  const int wm   = (w & 1) * 64;
  const int wn   = (w >> 1) * 64;
  const int l15  = lane & 15;
  const int quad = lane >> 4;

  const int o0  = blockIdx.x * 128;
  const int t0b = blockIdx.y * 128;

  f32x4 acc[4][4];
#pragma unroll
  for (int mi = 0; mi < 4; ++mi)
#pragma unroll
    for (int ni = 0; ni < 4; ++ni) acc[mi][ni] = {0.f, 0.f, 0.f, 0.f};

  for (int kk = 0; kk < DEMB; kk += 64) {
#pragma unroll
    for (int r = 0; r < 4; ++r) {
      int idx = tid + r * 256;
      int row = idx >> 3, c = (idx & 7) * 8;
      gll16(&W[(size_t)(o0 + row) * DEMB + kk + c], (unsigned short*)As + idx * 8);
      gll16(&X[(size_t)(t0b + row) * DEMB + kk + c], (unsigned short*)Bs + idx * 8);
    }
    __syncthreads();
#pragma unroll
    for (int k0 = 0; k0 < 64; k0 += 32) {
      FragU af[4], bfr[4];
#pragma unroll
      for (int mi = 0; mi < 4; ++mi)
        af[mi].u = *(const uint4*)&As[wm + mi * 16 + l15][k0 + quad * 8];
#pragma unroll
      for (int ni = 0; ni < 4; ++ni)
        bfr[ni].u = *(const uint4*)&Bs[wn + ni * 16 + l15][k0 + quad * 8];
#pragma unroll
      for (int mi = 0; mi < 4; ++mi)
#pragma unroll
        for (int ni = 0; ni < 4; ++ni)
          acc[mi][ni] = __builtin_amdgcn_mfma_f32_16x16x32_bf16(af[mi].b, bfr[ni].b, acc[mi][ni], 0, 0, 0);
    }
    __syncthreads();
  }

  // D rows: o = o0+wm+mi*16+quad*4+i (i consecutive); cols: token = t0b+wn+ni*16+l15
#pragma unroll
  for (int mi = 0; mi < 4; ++mi) {
    const int ob = o0 + wm + mi * 16 + quad * 4;
    const float4 bi = *(const float4*)&bias[ob];
    const int h_ = ob >> 6, db = ob & 63;
#pragma unroll
    for (int ni = 0; ni < 4; ++ni) {
      int token = t0b + wn + ni * 16 + l15;
      int b_ = token >> 11, s_ = token & 2047;
      ushort4 ov;
      ov.x = f2bf(acc[mi][ni][0] + bi.x);
      ov.y = f2bf(acc[mi][ni][1] + bi.y);
      ov.z = f2bf(acc[mi][ni][2] + bi.z);
      ov.w = f2bf(acc[mi][ni][3] + bi.w);
      *(ushort4*)&dst[(((size_t)b_ * NHEAD + h_) * SEQ + s_) * DK + db] = ov;
    }
  }
}

// ---------------------------------------------------------------------------
// k_vt: coalesced LDS transpose vh [bh][s][d] -> vt [bh][d][s] (once per head)
// ---------------------------------------------------------------------------
__global__ __launch_bounds__(256) void k_vt(const unsigned short* __restrict__ vh,
                                            unsigned short* __restrict__ vt)
{
  const int bh = blockIdx.y, s0 = blockIdx.x * 64;
  const size_t hoff = (size_t)bh * SEQ * DK;
  __shared__ unsigned short Ls[64][72];
  const int tid = threadIdx.x;
#pragma unroll
  for (int r = 0; r < 2; ++r) {
    int idx = tid + r * 256, row = idx >> 3, c = (idx & 7) * 8;
    uint4 v = *(const uint4*)&vh[hoff + (size_t)(s0 + row) * DK + c];
    *(uint4*)&Ls[row][c] = v;
  }
  __syncthreads();
#pragma unroll
  for (int r = 0; r < 2; ++r) {
    int idx = tid + r * 256, d = idx >> 3, c = (idx & 7) * 8;
    unsigned short tmp[8];
#pragma unroll
    for (int j = 0; j < 8; ++j) tmp[j] = Ls[c + j][d];
    *(uint4*)&vt[hoff + (size_t)d * SEQ + s0 + c] = *(const uint4*)tmp;
  }
}

// ---------------------------------------------------------------------------
// k_attn: per (head, 64 q-rows). Swapped QK operands compute S^T tiles so each
// lane holds 4 consecutive t values -> float4 P stores. Two-pass recompute for
// the row sums (cheaper than a 2nd 536MB round-trip). PV fused, V from vt via
// global_load_lds, accumulator in d-major orientation -> ushort4 blended store.
// ---------------------------------------------------------------------------
__global__ __launch_bounds__(256) void k_attn(
    const unsigned short* __restrict__ qh, const unsigned short* __restrict__ kh,
    const unsigned short* __restrict__ vt, unsigned short* __restrict__ blended,
    float* __restrict__ Pout)
{
  const int bh = blockIdx.y;
  const int s0 = blockIdx.x * 64;
  const size_t hoff = (size_t)bh * SEQ * DK;

  __shared__ unsigned short Qs[64][64];
  __shared__ unsigned short Ks[64][64];
  __shared__ unsigned short Vs[64][64];   // [d][t]
  __shared__ unsigned short Ps[64][72];   // [s][t], padded (16B row alignment kept)
  __shared__ float rowpart[4][64];
  __shared__ float recipS[64];

  const int tid  = threadIdx.x;
  const int lane = tid & 63;
  const int w    = tid >> 6;
  const int l15  = lane & 15;
  const int quad = lane >> 4;

  // stage Q once (linear: src offset == dest offset == idx*8 elems)
  gll16(&qh[hoff + (size_t)s0 * DK + (size_t)tid * 8], (unsigned short*)Qs + tid * 8);
  gll16(&qh[hoff + (size_t)s0 * DK + (size_t)(tid + 256) * 8], (unsigned short*)Qs + (tid + 256) * 8);
  __syncthreads();

  FragU qf[4][2];
#pragma unroll
  for (int mi = 0; mi < 4; ++mi)
#pragma unroll
    for (int k0 = 0; k0 < 2; ++k0)
      qf[mi][k0].u = *(const uint4*)&Qs[mi * 16 + l15][k0 * 32 + quad * 8];

  // ---- PASS 1: exp row sums ----
  float rs[4] = {0.f, 0.f, 0.f, 0.f};
  for (int t0 = 0; t0 < SEQ; t0 += 64) {
    __syncthreads();
    gll16(&kh[hoff + (size_t)t0 * DK + (size_t)tid * 8], (unsigned short*)Ks + tid * 8);
    gll16(&kh[hoff + (size_t)t0 * DK + (size_t)(tid + 256) * 8], (unsigned short*)Ks + (tid + 256) * 8);
    __syncthreads();
    FragU kf[2];
    kf[0].u = *(const uint4*)&Ks[w * 16 + l15][quad * 8];
    kf[1].u = *(const uint4*)&Ks[w * 16 + l15][32 + quad * 8];
#pragma unroll
    for (int mi = 0; mi < 4; ++mi) {
      f32x4 a = {0.f, 0.f, 0.f, 0.f};
      a = __builtin_amdgcn_mfma_f32_16x16x32_bf16(kf[0].b, qf[mi][0].b, a, 0, 0, 0);
      a = __builtin_amdgcn_mfma_f32_16x16x32_bf16(kf[1].b, qf[mi][1].b, a, 0, 0, 0);
#pragma unroll
      for (int i = 0; i < 4; ++i) rs[mi] += __expf(a[i] * 0.125f);
    }
  }
  // reduce: across quads (same s lives in lanes l15, l15+16, l15+32, l15+48)
#pragma unroll
  for (int mi = 0; mi < 4; ++mi) {
    float v = rs[mi];
    v += __shfl_xor(v, 16); v += __shfl_xor(v, 32);
    rs[mi] = v;
  }
  if (lane < 16) {
#pragma unroll
    for (int mi = 0; mi < 4; ++mi) rowpart[w][mi * 16 + lane] = rs[mi];
  }
  __syncthreads();
  if (tid < 64)
    recipS[tid] = 1.0f / (rowpart[0][tid] + rowpart[1][tid] + rowpart[2][tid] + rowpart[3][tid]);
  __syncthreads();
  float rcp[4];
#pragma unroll
  for (int mi = 0; mi < 4; ++mi) rcp[mi] = recipS[mi * 16 + l15];

  // ---- PASS 2: recompute, vectorized P write, fused PV ----
  f32x4 accpv[4];
#pragma unroll
  for (int mi = 0; mi < 4; ++mi) accpv[mi] = {0.f, 0.f, 0.f, 0.f};

  for (int t0 = 0; t0 < SEQ; t0 += 64) {
    __syncthreads();
    gll16(&kh[hoff + (size_t)t0 * DK + (size_t)tid * 8], (unsigned short*)Ks + tid * 8);
    gll16(&kh[hoff + (size_t)t0 * DK + (size_t)(tid + 256) * 8], (unsigned short*)Ks + (tid + 256) * 8);
    gll16(&vt[hoff + (size_t)(tid >> 3) * SEQ + t0 + (tid & 7) * 8], (unsigned short*)Vs + tid * 8);
    gll16(&vt[hoff + (size_t)((tid + 256) >> 3) * SEQ + t0 + (tid & 7) * 8], (unsigned short*)Vs + (tid + 256) * 8);
    __syncthreads();
    FragU kf[2];
    kf[0].u = *(const uint4*)&Ks[w * 16 + l15][quad * 8];
    kf[1].u = *(const uint4*)&Ks[w * 16 + l15][32 + quad * 8];
#pragma unroll
    for (int mi = 0; mi < 4; ++mi) {
      f32x4 a = {0.f, 0.f, 0.f, 0.f};
      a = __builtin_amdgcn_mfma_f32_16x16x32_bf16(kf[0].b, qf[mi][0].b, a, 0, 0, 0);
      a = __builtin_amdgcn_mfma_f32_16x16x32_bf16(kf[1].b, qf[mi][1].b, a, 0, 0, 0);
      // D: rows = t-local (w*16+quad*4+i, i consecutive), cols = s-local (mi*16+l15)
      float e0 = __expf(a[0] * 0.125f) * rcp[mi];
      float e1 = __expf(a[1] * 0.125f) * rcp[mi];
      float e2 = __expf(a[2] * 0.125f) * rcp[mi];
      float e3 = __expf(a[3] * 0.125f) * rcp[mi];
      float4 p4; p4.x = e0; p4.y = e1; p4.z = e2; p4.w = e3;
      *(float4*)&Pout[((size_t)bh * SEQ + s0 + mi * 16 + l15) * SEQ + t0 + w * 16 + quad * 4] = p4;
      ushort4 pb; pb.x = f2bf(e0); pb.y = f2bf(e1); pb.z = f2bf(e2); pb.w = f2bf(e3);
      *(ushort4*)&Ps[mi * 16 + l15][w * 16 + quad * 4] = pb;
    }
    __syncthreads();
    // PV with A=V (m=d), B=P (n=s): accpv rows = d (quad*4+i consecutive)
    FragU vf[2];
    vf[0].u = *(const uint4*)&Vs[w * 16 + l15][quad * 8];
    vf[1].u = *(const uint4*)&Vs[w * 16 + l15][32 + quad * 8];
#pragma unroll
    for (int mi = 0; mi < 4; ++mi) {
      FragU pf0, pf1;
      pf0.u = *(const uint4*)&Ps[mi * 16 + l15][quad * 8];
      pf1.u = *(const uint4*)&Ps[mi * 16 + l15][32 + quad * 8];
      accpv[mi] = __builtin_amdgcn_mfma_f32_16x16x32_bf16(vf[0].b, pf0.b, accpv[mi], 0, 0, 0);
      accpv[mi] = __builtin_amdgcn_mfma_f32_16x16x32_bf16(vf[1].b, pf1.b, accpv[mi], 0, 0, 0);
    }
  }

  // blended: d = w*16+quad*4+i (packed), s = mi*16+l15
  const int b_ = bh >> 4, h_ = bh & 15;
#pragma unroll
  for (int mi = 0; mi < 4; ++mi) {
    ushort4 ob;
    ob.x = f2bf(accpv[mi][0]); ob.y = f2bf(accpv[mi][1]);
    ob.z = f2bf(accpv[mi][2]); ob.w = f2bf(accpv[mi][3]);
    int token = b_ * SEQ + s0 + mi * 16 + l15;
    *(ushort4*)&blended[(size_t)token * DEMB + h_ * DK + w * 16 + quad * 4] = ob;
  }
}

// ---------------------------------------------------------------------------
// k_outproj: D[m=o][n=token] = sum_k Wo[o][k] * blended[token][k] + bo[o]
// float4 stores (4 consecutive o per lane).
// ---------------------------------------------------------------------------
__global__ __launch_bounds__(256) void k_outproj(
    const unsigned short* __restrict__ Wob, const unsigned short* __restrict__ blended,
    const float* __restrict__ bo, float* __restrict__ out)
{
  __shared__ unsigned short As[128][64];   // Wo rows (m = o)
  __shared__ unsigned short Bs[128][64];   // blended rows (n = token)

  const int tid  = threadIdx.x;
  const int lane = tid & 63;
  const int w    = tid >> 6;
  const int wm   = (w & 1) * 64;
  const int wn   = (w >> 1) * 64;
  const int l15  = lane & 15;
  const int quad = lane >> 4;

  const int o0  = blockIdx.x * 128;
  const int t0b = blockIdx.y * 128;

  f32x4 acc[4][4];
#pragma unroll
  for (int mi = 0; mi < 4; ++mi)
#pragma unroll
    for (int ni = 0; ni < 4; ++ni) acc[mi][ni] = {0.f, 0.f, 0.f, 0.f};

  for (int kk = 0; kk < DEMB; kk += 64) {
#pragma unroll
    for (int r = 0; r < 4; ++r) {
      int idx = tid + r * 256;
      int row = idx >> 3, c = (idx & 7) * 8;
      gll16(&Wob[(size_t)(o0 + row) * DEMB + kk + c], (unsigned short*)As + idx * 8);
      gll16(&blended[(size_t)(t0b + row) * DEMB + kk + c], (unsigned short*)Bs + idx * 8);
    }
    __syncthreads();
#pragma unroll
    for (int k0 = 0; k0 < 64; k0 += 32) {
      FragU af[4], bfr[4];
#pragma unroll
      for (int mi = 0; mi < 4; ++mi)
        af[mi].u = *(const uint4*)&As[wm + mi * 16 + l15][k0 + quad * 8];
#pragma unroll
      for (int ni = 0; ni < 4; ++ni)
        bfr[ni].u = *(const uint4*)&Bs[wn + ni * 16 + l15][k0 + quad * 8];
#pragma unroll
      for (int mi = 0; mi < 4; ++mi)
#pragma unroll
        for (int ni = 0; ni < 4; ++ni)
          acc[mi][ni] = __builtin_amdgcn_mfma_f32_16x16x32_bf16(af[mi].b, bfr[ni].b, acc[mi][ni], 0, 0, 0);
    }
    __syncthreads();
  }

#pragma unroll
  for (int mi = 0; mi < 4; ++mi) {
    const int ob = o0 + wm + mi * 16 + quad * 4;
    const float4 bi = *(const float4*)&bo[ob];
#pragma unroll
    for (int ni = 0; ni < 4; ++ni) {
      int token = t0b + wn + ni * 16 + l15;
      float4 ov;
      ov.x = acc[mi][ni][0] + bi.x;
      ov.y = acc[mi][ni][1] + bi.y;
      ov.z = acc[mi][ni][2] + bi.z;
      ov.w = acc[mi][ni][3] + bi.w;
      *(float4*)&out[(size_t)token * DEMB + ob] = ov;
    }
  }
}

// ---------------------------------------------------------------------------
extern "C" void kernel_launch(void* const* d_in, const int* in_sizes, int n_in,
                              void* d_out, int out_size, void* d_ws, size_t ws_size,
                              hipStream_t stream) {
  const float* Xq = (const float*)d_in[0];
  const float* Xk = (const float*)d_in[1];
  const float* Xv = (const float*)d_in[2];
  const float* Wq = (const float*)d_in[3];
  const float* bq = (const float*)d_in[4];
  const float* Wk = (const float*)d_in[5];
  const float* bk = (const float*)d_in[6];
  const float* Wv = (const float*)d_in[7];
  const float* bv = (const float*)d_in[8];
  const float* Wo = (const float*)d_in[9];
  const float* bo = (const float*)d_in[10];

  float* out  = (float*)d_out;
  float* Pout = out + OUT_ELEMS;

  // ws layout (bf16): 3 activations, 4 weights, qh/kh/vh/vt/blended
  unsigned short* Xqb = (unsigned short*)d_ws;
  unsigned short* Xkb = Xqb + OUT_ELEMS;
  unsigned short* Xvb = Xkb + OUT_ELEMS;
  unsigned short* Wqb = Xvb + OUT_ELEMS;
  unsigned short* Wkb = Wqb + (size_t)DEMB * DEMB;
  unsigned short* Wvb = Wkb + (size_t)DEMB * DEMB;
  unsigned short* Wob = Wvb + (size_t)DEMB * DEMB;
  unsigned short* qh      = Wob + (size_t)DEMB * DEMB;
  unsigned short* kh      = qh + OUT_ELEMS;
  unsigned short* vh      = kh + OUT_ELEMS;
  unsigned short* vt      = vh + OUT_ELEMS;
  unsigned short* blended = vt + OUT_ELEMS;

  k_cvt<<<dim3(1024, 7), 256, 0, stream>>>(Xq, Xk, Xv, Wq, Wk, Wv, Wo,
                                           Xqb, Xkb, Xvb, Wqb, Wkb, Wvb, Wob);
  k_proj<<<dim3(8, 32, 3), 256, 0, stream>>>(Xqb, Xkb, Xvb, Wqb, Wkb, Wvb,
                                             bq, bk, bv, qh, kh, vh);
  k_vt<<<dim3(32, 32), 256, 0, stream>>>(vh, vt);
  k_attn<<<dim3(SEQ / 64, BATCH * NHEAD), 256, 0, stream>>>(qh, kh, vt, blended, Pout);
  k_outproj<<<dim3(8, 32), 256, 0, stream>>>(Wob, blended, bo, out);
}